// Round 3
// baseline (340.247 us; speedup 1.0000x reference)
//
#include <hip/hip_runtime.h>
#include <hip/hip_bf16.h>
#include <stdint.h>

#define BB 4
#define SS 2048
#define HH 1024
#define NHH 16
#define HDD 64
#define M_TOT (BB*SS)          // 8192

// workspace layout (ushort/bf16 element offsets)
#define XB_OFF 0                              // hidden bf16 [8192][1024]
#define WT_OFF (M_TOT*HH)                     // Wq^T,Wk^T,Wv^T bf16 [3][N=1024][K=1024]
#define Q_OFF  (WT_OFF + 3*HH*HH)             // Q  [B][NH][S][HD]  (pre-scaled by 0.125*log2e!)
#define K_OFF  (Q_OFF + BB*NHH*SS*HDD)        // K  [B][NH][S][HD]
#define VT_OFF (K_OFF + BB*NHH*SS*HDD)        // Vt [B][NH][HD][S]  (transposed)

typedef short bf16x8 __attribute__((ext_vector_type(8)));
typedef float f32x4  __attribute__((ext_vector_type(4)));

__device__ inline unsigned short f2bf(float f){
  unsigned u = __float_as_uint(f);
  u += 0x7fffu + ((u >> 16) & 1u);   // RNE
  return (unsigned short)(u >> 16);
}
__device__ inline unsigned pk2bf(float lo, float hi){
  float2 t; t.x = lo; t.y = hi;
  __hip_bfloat162 h = __float22bfloat162_rn(t);
  return *(unsigned*)&h;
}

// async global->LDS, 16B per lane
__device__ __forceinline__ void ld_g2l_16(const unsigned short* g, unsigned short* l){
  __builtin_amdgcn_global_load_lds(
      (const __attribute__((address_space(1))) void*)g,
      (__attribute__((address_space(3))) void*)l, 16, 0, 0);
}

// ---------------- kernel 1a: X fp32 -> bf16 ----------------
__global__ void convert_x(const float* __restrict__ hs, unsigned short* __restrict__ xb){
  const int i = blockIdx.x*blockDim.x + threadIdx.x;
  float4 v = ((const float4*)hs)[i];
  ushort4 o;
  o.x = f2bf(v.x); o.y = f2bf(v.y); o.z = f2bf(v.z); o.w = f2bf(v.w);
  ((ushort4*)xb)[i] = o;
}

// ---------------- kernel 1b: W [K][N] fp32 -> WT [N][K] bf16 ----------------
__global__ void convert_wt(const float* __restrict__ wq, const float* __restrict__ wk,
                           const float* __restrict__ wv, unsigned short* __restrict__ wt){
  __shared__ unsigned short t[64][65];
  const int z = blockIdx.z;
  const float* W = (z==0) ? wq : ((z==1) ? wk : wv);
  unsigned short* WT = wt + z*HH*HH;
  const int kb = blockIdx.x*64, nb = blockIdx.y*64;
  const int tid = threadIdx.x;
  #pragma unroll
  for (int i = 0; i < 16; i++){
    const int idx = i*256 + tid;
    const int r = idx >> 6, c = idx & 63;
    t[r][c] = f2bf(W[(kb + r)*HH + nb + c]);
  }
  __syncthreads();
  #pragma unroll
  for (int i = 0; i < 16; i++){
    const int idx = i*256 + tid;
    const int n = idx >> 6, k = idx & 63;
    WT[(nb + n)*HH + kb + k] = t[k][n];
  }
}

// ---------------- kernel 2: QKV projection GEMM (m97 structure) ----------------
// z in {0,1} (Q,K): MFMA operands SWAPPED -> lane holds 4 consecutive d at fixed s
//   -> one ushort4 store per (mi,ni) + float4 bias/emb loads (was 64 scalar 2B stores).
// z==2 (V^T): original orientation already gives 4 consecutive s_ -> ushort4 store.
// z==0 (Q) output pre-scaled by 0.125*log2e so attention needs no per-score fma.
__global__ __launch_bounds__(256) void qkv_gemm(
    const unsigned short* __restrict__ ws16, unsigned short* __restrict__ wsq,
    const float* __restrict__ bq, const float* __restrict__ bk, const float* __restrict__ bv,
    const float* __restrict__ qe, const float* __restrict__ ke, const float* __restrict__ ve,
    const int* __restrict__ idxp){
  __shared__ unsigned short al[128*32];
  __shared__ unsigned short bl[128*32];

  const unsigned short* Xb = ws16 + XB_OFF;
  const int z = blockIdx.z;
  const unsigned short* Wt = ws16 + WT_OFF + z*HH*HH;
  const float* bias = (z==0) ? bq : ((z==1) ? bk : bv);
  const float* emb  = (z==0) ? qe : ((z==1) ? ke : ve);

  const int tid  = threadIdx.x;
  const int wv   = tid >> 6;
  const int ln   = tid & 63;
  const int quad = ln >> 4;
  const int l15  = ln & 15;
  const int m0 = blockIdx.x * 128;
  const int n0 = blockIdx.y * 128;
  const int wm = wv & 1, wn = wv >> 1;

  const int sr0 = wv*32 + (ln >> 2);
  const int sr1 = sr0 + 16;
  const int sk  = (ln & 3)*8;
  const unsigned short* ga0 = &Xb[(size_t)(m0 + sr0)*HH + sk];
  const unsigned short* ga1 = &Xb[(size_t)(m0 + sr1)*HH + sk];
  const unsigned short* gb0 = &Wt[(size_t)(n0 + sr0)*HH + sk];
  const unsigned short* gb1 = &Wt[(size_t)(n0 + sr1)*HH + sk];
  unsigned short* alb0 = &al[wv*1024];
  unsigned short* alb1 = &al[wv*1024 + 512];
  unsigned short* blb0 = &bl[wv*1024];
  unsigned short* blb1 = &bl[wv*1024 + 512];

  f32x4 acc[4][4] = {};

  for (int k0 = 0; k0 < HH; k0 += 32){
    __syncthreads();
    ld_g2l_16(ga0 + k0, alb0);
    ld_g2l_16(ga1 + k0, alb1);
    ld_g2l_16(gb0 + k0, blb0);
    ld_g2l_16(gb1 + k0, blb1);
    __syncthreads();

    bf16x8 af[4], bf[4];
    #pragma unroll
    for (int i = 0; i < 4; i++){
      af[i] = *(const bf16x8*)&al[(wm*64 + i*16 + l15)*32 + quad*8];
      bf[i] = *(const bf16x8*)&bl[(wn*64 + i*16 + l15)*32 + quad*8];
    }
    if (z == 2){
      #pragma unroll
      for (int mi = 0; mi < 4; mi++)
        #pragma unroll
        for (int ni = 0; ni < 4; ni++)
          acc[mi][ni] = __builtin_amdgcn_mfma_f32_16x16x32_bf16(af[mi], bf[ni], acc[mi][ni], 0, 0, 0);
    } else {
      // swapped: C^T tile -> lane holds (n=s-row=l15, m=d-col=quad*4+r)
      #pragma unroll
      for (int mi = 0; mi < 4; mi++)
        #pragma unroll
        for (int ni = 0; ni < 4; ni++)
          acc[mi][ni] = __builtin_amdgcn_mfma_f32_16x16x32_bf16(bf[ni], af[mi], acc[mi][ni], 0, 0, 0);
    }
  }

  const int index = idxp[0];
  if (z == 2){
    // V^T: [bh][d][s], lane holds 4 consecutive s_ -> ushort4
    #pragma unroll
    for (int ni = 0; ni < 4; ni++){
      const int n = n0 + wn*64 + ni*16 + l15;
      const float biasv = bias[n] + emb[index*HH + n];
      const int h = n >> 6, d = n & 63;
      #pragma unroll
      for (int mi = 0; mi < 4; mi++){
        const int g  = m0 + wm*64 + mi*16 + quad*4;   // 4 consecutive s (4-aligned)
        const int b_ = g >> 11;
        const int s_ = g & (SS - 1);
        const int bh = b_*NHH + h;
        const f32x4 a = acc[mi][ni];
        ushort4 o;
        o.x = f2bf(a[0] + biasv); o.y = f2bf(a[1] + biasv);
        o.z = f2bf(a[2] + biasv); o.w = f2bf(a[3] + biasv);
        *(ushort4*)&wsq[VT_OFF + (size_t)(bh*HDD + d)*SS + s_] = o;
      }
    }
  } else {
    // Q/K: [bh][s][d], swapped acc: lane holds 4 consecutive d at fixed s -> ushort4
    const float oscale = (z==0) ? 0.18033688011112042f : 1.0f;  // 0.125*log2(e)
    const size_t obase = (z==0) ? (size_t)Q_OFF : (size_t)K_OFF;
    #pragma unroll
    for (int mi = 0; mi < 4; mi++){
      const int sg = m0 + wm*64 + mi*16 + l15;        // s-row (from B-operand col)
      const int b_ = sg >> 11;
      const int s_ = sg & (SS - 1);
      #pragma unroll
      for (int ni = 0; ni < 4; ni++){
        const int nb = n0 + wn*64 + ni*16 + quad*4;   // 4 consecutive n (4-aligned)
        const int h  = nb >> 6, d0 = nb & 63;         // no h-cross (d0 % 4 == 0)
        const int bh = b_*NHH + h;
        const float4 b4 = *(const float4*)&bias[nb];
        const float4 e4 = *(const float4*)&emb[index*HH + nb];
        const f32x4 a = acc[mi][ni];
        ushort4 o;
        o.x = f2bf((a[0] + b4.x + e4.x) * oscale);
        o.y = f2bf((a[1] + b4.y + e4.y) * oscale);
        o.z = f2bf((a[2] + b4.z + e4.z) * oscale);
        o.w = f2bf((a[3] + b4.w + e4.w) * oscale);
        *(ushort4*)&wsq[obase + (size_t)(bh*SS + s_)*HDD + d0] = o;
      }
    }
  }
}

// ---------------- kernel 3: flash attention, 16q/wave, 8-wave blocks ----------------
// Block = 512 threads (8 waves) covering 128 q rows of one (b,h); wave w owns q rows
// [w*16,(w+1)*16). K/V staged per 32-kt chunk into double-buffered LDS: waves 0-3
// stage K, waves 4-7 stage V. K LDS XOR-swizzled via pre-swizzled global SOURCE
// (rule 21) -> conflict-free ds_read_b128; V^T rows 64B linear. mask*log2e staged
// once. Native exp2. Fixed-max softmax (Q pre-scaled; mask enters as MFMA C-init).
// XCD swizzle pins all 16 blocks of one (b,h) to one XCD (FETCH 139->24.6MB, R2).
// R3: va ds_reads hoisted BEFORE the S phase (off the exp2->PV critical path);
// T5 s_setprio(1) around MFMA clusters (wave role diversity exists: stage vs compute).
#define ST_P 40   // P^T row stride (shorts): 80B
__global__ __launch_bounds__(512) void attn_mfma(
    const unsigned short* __restrict__ ws16,
    const float* __restrict__ mask, float* __restrict__ out){
  __shared__ __align__(16) unsigned short kb[2][32*64];   // [kt][d], swizzled, 2x4KB
  __shared__ __align__(16) unsigned short vb[2][64*32];   // [d][kt], linear,   2x4KB
  __shared__ __align__(16) unsigned short pb[8][16*ST_P]; // per-wave P^T [q][kt], 10.24KB
  __shared__ __align__(16) float mlds[SS];                // mask row * log2e, 8KB

  const int tid  = threadIdx.x;
  const int wave = tid >> 6;
  const int lane = tid & 63;
  const int quad = lane >> 4;
  const int l15  = lane & 15;

  // XCD-aware swizzle (bijective: 1024 % 8 == 0)
  const int bid  = (blockIdx.x & 7)*128 + (blockIdx.x >> 3);
  const int qb   = bid & 15;                 // 16 q-blocks of 128 rows per bh
  const int bh   = bid >> 4;
  const int b    = bh >> 4, h = bh & 15;
  const int q0   = qb*128 + wave*16;         // this wave's first q row
  const float LOG2E = 1.4426950408889634f;

  const unsigned short* Qg = ws16 + Q_OFF  + (size_t)bh*SS*HDD;
  const unsigned short* Kg = ws16 + K_OFF  + (size_t)bh*SS*HDD;
  const unsigned short* Vg = ws16 + VT_OFF + (size_t)bh*HDD*SS;
  const float* maskB = mask + b*SS;

  // stage mask row * log2e (512 threads x float4 = 8KB)
  {
    float4 m4 = ((const float4*)maskB)[tid];
    m4.x*=LOG2E; m4.y*=LOG2E; m4.z*=LOG2E; m4.w*=LOG2E;
    *(float4*)&mlds[tid*4] = m4;
  }

  // resident Q fragments: B-operand (n=q=l15, k=d=h2*32+quad*8+j)
  bf16x8 aq[2];
  #pragma unroll
  for (int h2 = 0; h2 < 2; h2++)
    aq[h2] = *(const bf16x8*)(Qg + (size_t)(q0 + l15)*HDD + h2*32 + quad*8);

  // staging role split: waves 0-3 stage K (32 x 128B), waves 4-7 stage V (64 x 64B).
  const unsigned short* sSrc;
  unsigned short* sDst;
  int sAdv;
  if (tid < 256){
    const int kr = tid >> 3, kp = tid & 7;
    sSrc = Kg + (size_t)kr*HDD + ((((kp*16) ^ ((kr&7)<<4)))>>1);
    sDst = &kb[0][0] + tid*8;                // 16B per thread, linear
    sAdv = 32*HDD;
  } else {
    const int t = tid - 256;
    const int vr = t >> 2, vp = t & 3;
    sSrc = Vg + (size_t)vr*SS + vp*8;
    sDst = &vb[0][0] + t*8;
    sAdv = 32;
  }
  unsigned short* pw = &pb[wave][0];

  f32x4 O[4] = {};               // O^T: elem (d=dg*16+quad*4+r, q=l15)
  float lacc = 0.f;

  // prologue: stage chunk 0 into buffer 0 (syncthreads drains vmcnt)
  ld_g2l_16(sSrc, sDst);
  const unsigned short* sp = sSrc + sAdv;
  __syncthreads();

  #pragma unroll 2
  for (int ch = 0; ch < 64; ++ch){
    const int cur = ch & 1;
    const int ktb = ch*32;
    if (ch < 63){                // issue next-chunk stage BEFORE compute (overlap)
      ld_g2l_16(sp, sDst + (cur^1)*2048);
      sp += sAdv;
    }
    const unsigned short* kcur = &kb[cur][0];
    const unsigned short* vcur = &vb[cur][0];

    // V^T fragments FIRST (latency hides under S-MFMA + exp2; off critical path)
    bf16x8 va[4];
    #pragma unroll
    for (int dg = 0; dg < 4; dg++)
      va[dg] = *(const bf16x8*)&vcur[(dg*16 + l15)*32 + quad*8];

    // K fragments: A-operand (m=kt=fi*16+l15, k=d), swizzled read (conflict-free)
    bf16x8 ka[2][2];
    #pragma unroll
    for (int fi = 0; fi < 2; fi++)
      #pragma unroll
      for (int h2 = 0; h2 < 2; h2++){
        const int colb = (h2*64 + quad*16) ^ ((l15 & 7) << 4);
        ka[fi][h2] = *(const bf16x8*)&kcur[(fi*16 + l15)*64 + (colb>>1)];
      }

    // S^T = K·Q^T with C init = mask*log2e -> p = exp2(st) -> P^T to LDS
    #pragma unroll
    for (int fi = 0; fi < 2; fi++){
      f32x4 st = *(const f32x4*)&mlds[ktb + fi*16 + quad*4];  // same-addr broadcast
      __builtin_amdgcn_s_setprio(1);
      st = __builtin_amdgcn_mfma_f32_16x16x32_bf16(ka[fi][0], aq[0], st, 0,0,0);
      st = __builtin_amdgcn_mfma_f32_16x16x32_bf16(ka[fi][1], aq[1], st, 0,0,0);
      __builtin_amdgcn_s_setprio(0);
      f32x4 p;
      #pragma unroll
      for (int r = 0; r < 4; r++) p[r] = __builtin_amdgcn_exp2f(st[r]);
      lacc += (p[0] + p[1]) + (p[2] + p[3]);
      uint2 w; w.x = pk2bf(p[0], p[1]); w.y = pk2bf(p[2], p[3]);
      *(uint2*)&pw[l15*ST_P + fi*16 + quad*4] = w;
    }

    // O^T += V^T · P^T  (intra-wave LDS round-trip, wave-ordered, no barrier)
    {
      bf16x8 bp = *(const bf16x8*)&pw[l15*ST_P + quad*8];
      __builtin_amdgcn_s_setprio(1);
      #pragma unroll
      for (int dg = 0; dg < 4; dg++)
        O[dg] = __builtin_amdgcn_mfma_f32_16x16x32_bf16(va[dg], bp, O[dg], 0,0,0);
      __builtin_amdgcn_s_setprio(0);
    }

    __syncthreads();   // all waves done reading cur; next-chunk stage drained
  }

  // row sum: reduce lacc across quads (lanes with same l15 share q)
  float lq = lacc;
  lq += __shfl_xor(lq, 16);
  lq += __shfl_xor(lq, 32);
  const float inv = 1.0f / lq;

  // epilogue: scale by 1/l, write ctx [B,S,H] fp32 as float4 per dg
  float* op = out + ((size_t)b*SS + q0 + l15)*HH + h*HDD + quad*4;
  #pragma unroll
  for (int dg = 0; dg < 4; dg++){
    f32x4 v = O[dg];
    float4 o; o.x = v[0]*inv; o.y = v[1]*inv; o.z = v[2]*inv; o.w = v[3]*inv;
    *(float4*)(op + dg*16) = o;
  }
}

extern "C" void kernel_launch(void* const* d_in, const int* in_sizes, int n_in,
                              void* d_out, int out_size, void* d_ws, size_t ws_size,
                              hipStream_t stream){
  const float* hs   = (const float*)d_in[0];
  const float* mask = (const float*)d_in[1];
  const float* Wq   = (const float*)d_in[2];
  const float* bq   = (const float*)d_in[3];
  const float* Wk   = (const float*)d_in[4];
  const float* bk   = (const float*)d_in[5];
  const float* Wv   = (const float*)d_in[6];
  const float* bv   = (const float*)d_in[7];
  const float* qe   = (const float*)d_in[8];
  const float* ke   = (const float*)d_in[9];
  const float* ve   = (const float*)d_in[10];
  const int*   idx  = (const int*)d_in[11];
  unsigned short* ws16 = (unsigned short*)d_ws;
  float* out = (float*)d_out;

  convert_x<<<M_TOT*HH/4/256, 256, 0, stream>>>(hs, ws16 + XB_OFF);
  dim3 gt(HH/64, HH/64, 3);
  convert_wt<<<gt, 256, 0, stream>>>(Wq, Wk, Wv, ws16 + WT_OFF);

  dim3 g2(M_TOT/128, HH/128, 3);
  qkv_gemm<<<g2, 256, 0, stream>>>(ws16, ws16, bq, bk, bv, qe, ke, ve, idx);

  attn_mfma<<<BB*NHH*SS/128, 512, 0, stream>>>(ws16, mask, out);
}

// Round 4
// 326.016 us; speedup vs baseline: 1.0436x; 1.0436x over previous
//
#include <hip/hip_runtime.h>
#include <hip/hip_bf16.h>
#include <stdint.h>

#define BB 4
#define SS 2048
#define HH 1024
#define NHH 16
#define HDD 64
#define M_TOT (BB*SS)          // 8192

// workspace layout (ushort/bf16 element offsets)
#define XB_OFF 0                              // hidden bf16 [8192][1024]
#define WT_OFF (M_TOT*HH)                     // Wq^T,Wk^T,Wv^T bf16 [3][N=1024][K=1024]
#define Q_OFF  (WT_OFF + 3*HH*HH)             // Q  [B][NH][S][HD]  (pre-scaled by 0.125*log2e!)
#define K_OFF  (Q_OFF + BB*NHH*SS*HDD)        // K  [B][NH][S][HD]
#define VT_OFF (K_OFF + BB*NHH*SS*HDD)        // Vt [B][NH][HD][S]  (transposed)

typedef short bf16x8 __attribute__((ext_vector_type(8)));
typedef float f32x4  __attribute__((ext_vector_type(4)));

__device__ inline unsigned short f2bf(float f){
  unsigned u = __float_as_uint(f);
  u += 0x7fffu + ((u >> 16) & 1u);   // RNE
  return (unsigned short)(u >> 16);
}
__device__ inline unsigned pk2bf(float lo, float hi){
  float2 t; t.x = lo; t.y = hi;
  __hip_bfloat162 h = __float22bfloat162_rn(t);
  return *(unsigned*)&h;
}

// async global->LDS, 16B per lane
__device__ __forceinline__ void ld_g2l_16(const unsigned short* g, unsigned short* l){
  __builtin_amdgcn_global_load_lds(
      (const __attribute__((address_space(1))) void*)g,
      (__attribute__((address_space(3))) void*)l, 16, 0, 0);
}

// ---------------- kernel 1a: X fp32 -> bf16 ----------------
__global__ void convert_x(const float* __restrict__ hs, unsigned short* __restrict__ xb){
  const int i = blockIdx.x*blockDim.x + threadIdx.x;
  float4 v = ((const float4*)hs)[i];
  ushort4 o;
  o.x = f2bf(v.x); o.y = f2bf(v.y); o.z = f2bf(v.z); o.w = f2bf(v.w);
  ((ushort4*)xb)[i] = o;
}

// ---------------- kernel 1b: W [K][N] fp32 -> WT [N][K] bf16 ----------------
__global__ void convert_wt(const float* __restrict__ wq, const float* __restrict__ wk,
                           const float* __restrict__ wv, unsigned short* __restrict__ wt){
  __shared__ unsigned short t[64][65];
  const int z = blockIdx.z;
  const float* W = (z==0) ? wq : ((z==1) ? wk : wv);
  unsigned short* WT = wt + z*HH*HH;
  const int kb = blockIdx.x*64, nb = blockIdx.y*64;
  const int tid = threadIdx.x;
  #pragma unroll
  for (int i = 0; i < 16; i++){
    const int idx = i*256 + tid;
    const int r = idx >> 6, c = idx & 63;
    t[r][c] = f2bf(W[(kb + r)*HH + nb + c]);
  }
  __syncthreads();
  #pragma unroll
  for (int i = 0; i < 16; i++){
    const int idx = i*256 + tid;
    const int n = idx >> 6, k = idx & 63;
    WT[(nb + n)*HH + kb + k] = t[k][n];
  }
}

// ---------------- kernel 2: QKV projection GEMM ----------------
// R4: double-buffered LDS + stage-ahead (attn-style T3-minimal pipeline):
//   issue stage(k+32) into alt buffer BEFORE compute(k); ONE barrier per k-step
//   (was: single buffer, 2 barriers/step -> zero intra-block overlap, latency-bound
//   at 11% occupancy per R3 counters).
// z in {0,1} (Q,K): MFMA operands SWAPPED -> lane holds 4 consecutive d at fixed s
//   -> one ushort4 store per (mi,ni) + float4 bias/emb loads.
// z==2 (V^T): original orientation gives 4 consecutive s_ -> ushort4 store.
// z==0 (Q) output pre-scaled by 0.125*log2e so attention needs no per-score fma.
__global__ __launch_bounds__(256) void qkv_gemm(
    const unsigned short* __restrict__ ws16, unsigned short* __restrict__ wsq,
    const float* __restrict__ bq, const float* __restrict__ bk, const float* __restrict__ bv,
    const float* __restrict__ qe, const float* __restrict__ ke, const float* __restrict__ ve,
    const int* __restrict__ idxp){
  __shared__ unsigned short al[2*128*32];   // 2 x 8KB
  __shared__ unsigned short bl[2*128*32];   // 2 x 8KB

  const unsigned short* Xb = ws16 + XB_OFF;
  const int z = blockIdx.z;
  const unsigned short* Wt = ws16 + WT_OFF + z*HH*HH;
  const float* bias = (z==0) ? bq : ((z==1) ? bk : bv);
  const float* emb  = (z==0) ? qe : ((z==1) ? ke : ve);

  const int tid  = threadIdx.x;
  const int wv   = tid >> 6;
  const int ln   = tid & 63;
  const int quad = ln >> 4;
  const int l15  = ln & 15;
  const int m0 = blockIdx.x * 128;
  const int n0 = blockIdx.y * 128;
  const int wm = wv & 1, wn = wv >> 1;

  const int sr0 = wv*32 + (ln >> 2);
  const int sr1 = sr0 + 16;
  const int sk  = (ln & 3)*8;
  const unsigned short* ga0 = &Xb[(size_t)(m0 + sr0)*HH + sk];
  const unsigned short* ga1 = &Xb[(size_t)(m0 + sr1)*HH + sk];
  const unsigned short* gb0 = &Wt[(size_t)(n0 + sr0)*HH + sk];
  const unsigned short* gb1 = &Wt[(size_t)(n0 + sr1)*HH + sk];
  unsigned short* alb0 = &al[wv*1024];
  unsigned short* alb1 = &al[wv*1024 + 512];
  unsigned short* blb0 = &bl[wv*1024];
  unsigned short* blb1 = &bl[wv*1024 + 512];

  f32x4 acc[4][4] = {};

  // prologue: stage k0=0 into buffer 0 (__syncthreads drains vmcnt)
  ld_g2l_16(ga0, alb0);
  ld_g2l_16(ga1, alb1);
  ld_g2l_16(gb0, blb0);
  ld_g2l_16(gb1, blb1);
  __syncthreads();

  #pragma unroll 2
  for (int k0 = 0; k0 < HH; k0 += 32){
    const int cur = (k0 >> 5) & 1;
    if (k0 + 32 < HH){           // issue next-step stage BEFORE compute (overlap)
      const int nxt = cur ^ 1;
      ld_g2l_16(ga0 + k0 + 32, alb0 + nxt*4096);
      ld_g2l_16(ga1 + k0 + 32, alb1 + nxt*4096);
      ld_g2l_16(gb0 + k0 + 32, blb0 + nxt*4096);
      ld_g2l_16(gb1 + k0 + 32, blb1 + nxt*4096);
    }
    const unsigned short* alc = &al[cur*4096];
    const unsigned short* blc = &bl[cur*4096];

    bf16x8 af[4], bf[4];
    #pragma unroll
    for (int i = 0; i < 4; i++){
      af[i] = *(const bf16x8*)&alc[(wm*64 + i*16 + l15)*32 + quad*8];
      bf[i] = *(const bf16x8*)&blc[(wn*64 + i*16 + l15)*32 + quad*8];
    }
    if (z == 2){
      #pragma unroll
      for (int mi = 0; mi < 4; mi++)
        #pragma unroll
        for (int ni = 0; ni < 4; ni++)
          acc[mi][ni] = __builtin_amdgcn_mfma_f32_16x16x32_bf16(af[mi], bf[ni], acc[mi][ni], 0, 0, 0);
    } else {
      // swapped: C^T tile -> lane holds (n=s-row=l15, m=d-col=quad*4+r)
      #pragma unroll
      for (int mi = 0; mi < 4; mi++)
        #pragma unroll
        for (int ni = 0; ni < 4; ni++)
          acc[mi][ni] = __builtin_amdgcn_mfma_f32_16x16x32_bf16(bf[ni], af[mi], acc[mi][ni], 0, 0, 0);
    }
    __syncthreads();   // all waves done reading cur; next-step stage drained
  }

  const int index = idxp[0];
  if (z == 2){
    // V^T: [bh][d][s], lane holds 4 consecutive s_ -> ushort4
    #pragma unroll
    for (int ni = 0; ni < 4; ni++){
      const int n = n0 + wn*64 + ni*16 + l15;
      const float biasv = bias[n] + emb[index*HH + n];
      const int h = n >> 6, d = n & 63;
      #pragma unroll
      for (int mi = 0; mi < 4; mi++){
        const int g  = m0 + wm*64 + mi*16 + quad*4;   // 4 consecutive s (4-aligned)
        const int b_ = g >> 11;
        const int s_ = g & (SS - 1);
        const int bh = b_*NHH + h;
        const f32x4 a = acc[mi][ni];
        ushort4 o;
        o.x = f2bf(a[0] + biasv); o.y = f2bf(a[1] + biasv);
        o.z = f2bf(a[2] + biasv); o.w = f2bf(a[3] + biasv);
        *(ushort4*)&wsq[VT_OFF + (size_t)(bh*HDD + d)*SS + s_] = o;
      }
    }
  } else {
    // Q/K: [bh][s][d], swapped acc: lane holds 4 consecutive d at fixed s -> ushort4
    const float oscale = (z==0) ? 0.18033688011112042f : 1.0f;  // 0.125*log2(e)
    const size_t obase = (z==0) ? (size_t)Q_OFF : (size_t)K_OFF;
    #pragma unroll
    for (int mi = 0; mi < 4; mi++){
      const int sg = m0 + wm*64 + mi*16 + l15;        // s-row (from B-operand col)
      const int b_ = sg >> 11;
      const int s_ = sg & (SS - 1);
      #pragma unroll
      for (int ni = 0; ni < 4; ni++){
        const int nb = n0 + wn*64 + ni*16 + quad*4;   // 4 consecutive n (4-aligned)
        const int h  = nb >> 6, d0 = nb & 63;         // no h-cross (d0 % 4 == 0)
        const int bh = b_*NHH + h;
        const float4 b4 = *(const float4*)&bias[nb];
        const float4 e4 = *(const float4*)&emb[index*HH + nb];
        const f32x4 a = acc[mi][ni];
        ushort4 o;
        o.x = f2bf((a[0] + b4.x + e4.x) * oscale);
        o.y = f2bf((a[1] + b4.y + e4.y) * oscale);
        o.z = f2bf((a[2] + b4.z + e4.z) * oscale);
        o.w = f2bf((a[3] + b4.w + e4.w) * oscale);
        *(ushort4*)&wsq[obase + (size_t)(bh*SS + s_)*HDD + d0] = o;
      }
    }
  }
}

// ---------------- kernel 3: flash attention, 16q/wave, 8-wave blocks ----------------
// (R2 known-good version: 112 µs measured. R3's setprio/va-hoist reverted — lockstep
// barrier structure is the regime where setprio measured null/negative.)
#define ST_P 40   // P^T row stride (shorts): 80B
__global__ __launch_bounds__(512, 6) void attn_mfma(
    const unsigned short* __restrict__ ws16,
    const float* __restrict__ mask, float* __restrict__ out){
  __shared__ __align__(16) unsigned short kb[2][32*64];   // [kt][d], swizzled, 2x4KB
  __shared__ __align__(16) unsigned short vb[2][64*32];   // [d][kt], linear,   2x4KB
  __shared__ __align__(16) unsigned short pb[8][16*ST_P]; // per-wave P^T [q][kt], 10.24KB
  __shared__ __align__(16) float mlds[SS];                // mask row * log2e, 8KB

  const int tid  = threadIdx.x;
  const int wave = tid >> 6;
  const int lane = tid & 63;
  const int quad = lane >> 4;
  const int l15  = lane & 15;

  // XCD-aware swizzle (bijective: 1024 % 8 == 0): each head's 16 blocks on one XCD.
  const int bid  = (blockIdx.x & 7)*128 + (blockIdx.x >> 3);
  const int qb   = bid & 15;                 // 16 q-blocks of 128 rows per bh
  const int bh   = bid >> 4;
  const int b    = bh >> 4, h = bh & 15;
  const int q0   = qb*128 + wave*16;         // this wave's first q row
  const float LOG2E = 1.4426950408889634f;

  const unsigned short* Qg = ws16 + Q_OFF  + (size_t)bh*SS*HDD;
  const unsigned short* Kg = ws16 + K_OFF  + (size_t)bh*SS*HDD;
  const unsigned short* Vg = ws16 + VT_OFF + (size_t)bh*HDD*SS;
  const float* maskB = mask + b*SS;

  // stage mask row * log2e (512 threads x float4 = 8KB)
  {
    float4 m4 = ((const float4*)maskB)[tid];
    m4.x*=LOG2E; m4.y*=LOG2E; m4.z*=LOG2E; m4.w*=LOG2E;
    *(float4*)&mlds[tid*4] = m4;
  }

  // resident Q fragments: B-operand (n=q=l15, k=d=h2*32+quad*8+j)
  bf16x8 aq[2];
  #pragma unroll
  for (int h2 = 0; h2 < 2; h2++)
    aq[h2] = *(const bf16x8*)(Qg + (size_t)(q0 + l15)*HDD + h2*32 + quad*8);

  // staging role split: waves 0-3 stage K (32 x 128B), waves 4-7 stage V (64 x 64B).
  // K source col pre-XOR-swizzled so linear dest yields LDS[kt][col ^ ((kt&7)<<4)].
  const unsigned short* sSrc;
  unsigned short* sDst;
  int sAdv;
  if (tid < 256){
    const int kr = tid >> 3, kp = tid & 7;
    sSrc = Kg + (size_t)kr*HDD + ((((kp*16) ^ ((kr&7)<<4)))>>1);
    sDst = &kb[0][0] + tid*8;                // 16B per thread, linear
    sAdv = 32*HDD;
  } else {
    const int t = tid - 256;
    const int vr = t >> 2, vp = t & 3;
    sSrc = Vg + (size_t)vr*SS + vp*8;
    sDst = &vb[0][0] + t*8;
    sAdv = 32;
  }
  unsigned short* pw = &pb[wave][0];

  f32x4 O[4] = {};               // O^T: elem (d=dg*16+quad*4+r, q=l15)
  float lacc = 0.f;

  // prologue: stage chunk 0 into buffer 0 (syncthreads drains vmcnt)
  ld_g2l_16(sSrc, sDst);
  const unsigned short* sp = sSrc + sAdv;
  __syncthreads();

  #pragma unroll 2
  for (int ch = 0; ch < 64; ++ch){
    const int cur = ch & 1;
    const int ktb = ch*32;
    if (ch < 63){                // issue next-chunk stage BEFORE compute (overlap)
      ld_g2l_16(sp, sDst + (cur^1)*2048);
      sp += sAdv;
    }
    const unsigned short* kcur = &kb[cur][0];
    const unsigned short* vcur = &vb[cur][0];

    // K fragments: A-operand (m=kt=fi*16+l15, k=d), swizzled read (conflict-free)
    bf16x8 ka[2][2];
    #pragma unroll
    for (int fi = 0; fi < 2; fi++)
      #pragma unroll
      for (int h2 = 0; h2 < 2; h2++){
        const int colb = (h2*64 + quad*16) ^ ((l15 & 7) << 4);
        ka[fi][h2] = *(const bf16x8*)&kcur[(fi*16 + l15)*64 + (colb>>1)];
      }

    // S^T = K·Q^T with C init = mask*log2e -> p = exp2(st) -> P^T to LDS
    #pragma unroll
    for (int fi = 0; fi < 2; fi++){
      f32x4 st = *(const f32x4*)&mlds[ktb + fi*16 + quad*4];  // same-addr broadcast
      st = __builtin_amdgcn_mfma_f32_16x16x32_bf16(ka[fi][0], aq[0], st, 0,0,0);
      st = __builtin_amdgcn_mfma_f32_16x16x32_bf16(ka[fi][1], aq[1], st, 0,0,0);
      f32x4 p;
      #pragma unroll
      for (int r = 0; r < 4; r++) p[r] = __builtin_amdgcn_exp2f(st[r]);
      lacc += (p[0] + p[1]) + (p[2] + p[3]);
      uint2 w; w.x = pk2bf(p[0], p[1]); w.y = pk2bf(p[2], p[3]);
      *(uint2*)&pw[l15*ST_P + fi*16 + quad*4] = w;
    }

    // V^T fragments: A-operand (m=d=dg*16+l15, k=kt=quad*8+j), 64B rows
    bf16x8 va[4];
    #pragma unroll
    for (int dg = 0; dg < 4; dg++)
      va[dg] = *(const bf16x8*)&vcur[(dg*16 + l15)*32 + quad*8];

    // O^T += V^T · P^T  (intra-wave LDS round-trip, wave-ordered, no barrier)
    {
      bf16x8 bp = *(const bf16x8*)&pw[l15*ST_P + quad*8];
      #pragma unroll
      for (int dg = 0; dg < 4; dg++)
        O[dg] = __builtin_amdgcn_mfma_f32_16x16x32_bf16(va[dg], bp, O[dg], 0,0,0);
    }

    __syncthreads();   // all waves done reading cur; next-chunk stage drained
  }

  // row sum: reduce lacc across quads (lanes with same l15 share q)
  float lq = lacc;
  lq += __shfl_xor(lq, 16);
  lq += __shfl_xor(lq, 32);
  const float inv = 1.0f / lq;

  // epilogue: scale by 1/l, write ctx [B,S,H] fp32 as float4 per dg
  float* op = out + ((size_t)b*SS + q0 + l15)*HH + h*HDD + quad*4;
  #pragma unroll
  for (int dg = 0; dg < 4; dg++){
    f32x4 v = O[dg];
    float4 o; o.x = v[0]*inv; o.y = v[1]*inv; o.z = v[2]*inv; o.w = v[3]*inv;
    *(float4*)(op + dg*16) = o;
  }
}

extern "C" void kernel_launch(void* const* d_in, const int* in_sizes, int n_in,
                              void* d_out, int out_size, void* d_ws, size_t ws_size,
                              hipStream_t stream){
  const float* hs   = (const float*)d_in[0];
  const float* mask = (const float*)d_in[1];
  const float* Wq   = (const float*)d_in[2];
  const float* bq   = (const float*)d_in[3];
  const float* Wk   = (const float*)d_in[4];
  const float* bk   = (const float*)d_in[5];
  const float* Wv   = (const float*)d_in[6];
  const float* bv   = (const float*)d_in[7];
  const float* qe   = (const float*)d_in[8];
  const float* ke   = (const float*)d_in[9];
  const float* ve   = (const float*)d_in[10];
  const int*   idx  = (const int*)d_in[11];
  unsigned short* ws16 = (unsigned short*)d_ws;
  float* out = (float*)d_out;

  convert_x<<<M_TOT*HH/4/256, 256, 0, stream>>>(hs, ws16 + XB_OFF);
  dim3 gt(HH/64, HH/64, 3);
  convert_wt<<<gt, 256, 0, stream>>>(Wq, Wk, Wv, ws16 + WT_OFF);

  dim3 g2(M_TOT/128, HH/128, 3);
  qkv_gemm<<<g2, 256, 0, stream>>>(ws16, ws16, bq, bk, bv, qe, ke, ve, idx);

  attn_mfma<<<BB*NHH*SS/128, 512, 0, stream>>>(ws16, mask, out);
}

// Round 5
// 316.320 us; speedup vs baseline: 1.0756x; 1.0307x over previous
//
#include <hip/hip_runtime.h>
#include <hip/hip_bf16.h>
#include <stdint.h>

#define BB 4
#define SS 2048
#define HH 1024
#define NHH 16
#define HDD 64
#define M_TOT (BB*SS)          // 8192

// workspace layout (ushort/bf16 element offsets)
#define XB_OFF 0                              // hidden bf16 [8192][1024]
#define WT_OFF (M_TOT*HH)                     // Wq^T,Wk^T,Wv^T bf16 [3][N=1024][K=1024]
#define Q_OFF  (WT_OFF + 3*HH*HH)             // Q  [B][NH][S][HD]  (pre-scaled by 0.125*log2e!)
#define K_OFF  (Q_OFF + BB*NHH*SS*HDD)        // K  [B][NH][S][HD]
#define VT_OFF (K_OFF + BB*NHH*SS*HDD)        // Vt [B][NH][HD][S]  (transposed)

typedef short bf16x8 __attribute__((ext_vector_type(8)));
typedef float f32x4  __attribute__((ext_vector_type(4)));

__device__ inline unsigned short f2bf(float f){
  unsigned u = __float_as_uint(f);
  u += 0x7fffu + ((u >> 16) & 1u);   // RNE
  return (unsigned short)(u >> 16);
}
__device__ inline unsigned pk2bf(float lo, float hi){
  float2 t; t.x = lo; t.y = hi;
  __hip_bfloat162 h = __float22bfloat162_rn(t);
  return *(unsigned*)&h;
}

// async global->LDS, 16B per lane
__device__ __forceinline__ void ld_g2l_16(const unsigned short* g, unsigned short* l){
  __builtin_amdgcn_global_load_lds(
      (const __attribute__((address_space(1))) void*)g,
      (__attribute__((address_space(3))) void*)l, 16, 0, 0);
}

// ---------------- kernel 1a: X fp32 -> bf16 ----------------
__global__ void convert_x(const float* __restrict__ hs, unsigned short* __restrict__ xb){
  const int i = blockIdx.x*blockDim.x + threadIdx.x;
  float4 v = ((const float4*)hs)[i];
  ushort4 o;
  o.x = f2bf(v.x); o.y = f2bf(v.y); o.z = f2bf(v.z); o.w = f2bf(v.w);
  ((ushort4*)xb)[i] = o;
}

// ---------------- kernel 1b: W [K][N] fp32 -> WT [N][K] bf16 ----------------
__global__ void convert_wt(const float* __restrict__ wq, const float* __restrict__ wk,
                           const float* __restrict__ wv, unsigned short* __restrict__ wt){
  __shared__ unsigned short t[64][65];
  const int z = blockIdx.z;
  const float* W = (z==0) ? wq : ((z==1) ? wk : wv);
  unsigned short* WT = wt + z*HH*HH;
  const int kb = blockIdx.x*64, nb = blockIdx.y*64;
  const int tid = threadIdx.x;
  #pragma unroll
  for (int i = 0; i < 16; i++){
    const int idx = i*256 + tid;
    const int r = idx >> 6, c = idx & 63;
    t[r][c] = f2bf(W[(kb + r)*HH + nb + c]);
  }
  __syncthreads();
  #pragma unroll
  for (int i = 0; i < 16; i++){
    const int idx = i*256 + tid;
    const int n = idx >> 6, k = idx & 63;
    WT[(nb + n)*HH + kb + k] = t[k][n];
  }
}

// ---------------- kernel 2: QKV projection GEMM ----------------
// R5: (a) 3-buffer LDS pipeline, depth-2 prefetch, COUNTED vmcnt(4) (never 0 in
//     main loop — T4), raw s_barrier, ONE barrier/iter. Order per iter:
//     vmcnt(4) -> s_barrier -> stage(k+2) -> ds_read(buf k%3) -> MFMA.
//     WAR hazard OK: stage(k+2) writes the buffer last read in iter k-1; every
//     wave passed barrier k only after its k-1 ds_reads completed (lgkmcnt before
//     the k-1 MFMAs, which precede barrier k in program order).
// (b) LDS XOR swizzle (16B-col: p' = p ^ ((row>>1)&3)) on A and B tiles via
//     pre-swizzled global SOURCE (rule 21) -> 8-way ds_read_b128 conflict -> 2-way.
// z in {0,1}: MFMA operands swapped -> lane holds 4 consecutive d -> ushort4 stores.
// z==2 (V^T): lane holds 4 consecutive s -> ushort4 stores.
__global__ __launch_bounds__(256) void qkv_gemm(
    const unsigned short* __restrict__ ws16, unsigned short* __restrict__ wsq,
    const float* __restrict__ bq, const float* __restrict__ bk, const float* __restrict__ bv,
    const float* __restrict__ qe, const float* __restrict__ ke, const float* __restrict__ ve,
    const int* __restrict__ idxp){
  __shared__ unsigned short al[3*128*32];   // 3 x 8KB
  __shared__ unsigned short bl[3*128*32];   // 3 x 8KB

  const unsigned short* Xb = ws16 + XB_OFF;
  const int z = blockIdx.z;
  const unsigned short* Wt = ws16 + WT_OFF + z*HH*HH;
  const float* bias = (z==0) ? bq : ((z==1) ? bk : bv);
  const float* emb  = (z==0) ? qe : ((z==1) ? ke : ve);

  const int tid  = threadIdx.x;
  const int wv   = tid >> 6;
  const int ln   = tid & 63;
  const int quad = ln >> 4;
  const int l15  = ln & 15;
  const int m0 = blockIdx.x * 128;
  const int n0 = blockIdx.y * 128;
  const int wm = wv & 1, wn = wv >> 1;
  const int swz = (l15 >> 1) & 3;            // read-side 16B-col XOR

  // staging: wave wv stages rows [wv*32, wv*32+32) of each 128x32 tile.
  // source piece pre-swizzled: physical piece (ln&3) at row sr holds logical
  // piece (ln&3) ^ ((sr>>1)&3); (sr>>1)&3 == (ln>>3)&3 for both sr0 and sr1.
  const int sr0 = wv*32 + (ln >> 2);
  const int sr1 = sr0 + 16;
  const int sk  = (((ln & 3) ^ ((ln >> 3) & 3))) * 8;
  const unsigned short* ga0 = &Xb[(size_t)(m0 + sr0)*HH + sk];
  const unsigned short* ga1 = &Xb[(size_t)(m0 + sr1)*HH + sk];
  const unsigned short* gb0 = &Wt[(size_t)(n0 + sr0)*HH + sk];
  const unsigned short* gb1 = &Wt[(size_t)(n0 + sr1)*HH + sk];
  unsigned short* alw = &al[wv*1024];        // wave's linear dest (+lane*16B)
  unsigned short* blw = &bl[wv*1024];

  f32x4 acc[4][4] = {};

  // prologue: stage k=0 -> buf0, k=1 -> buf1 (8 loads in flight)
  ld_g2l_16(ga0,      alw);        ld_g2l_16(ga1,      alw + 512);
  ld_g2l_16(gb0,      blw);        ld_g2l_16(gb1,      blw + 512);
  ld_g2l_16(ga0 + 32, alw + 4096); ld_g2l_16(ga1 + 32, alw + 4096 + 512);
  ld_g2l_16(gb0 + 32, blw + 4096); ld_g2l_16(gb1 + 32, blw + 4096 + 512);

#define K_ITER(K, CUR, SB, DO_STAGE, VM)                                      \
  {                                                                           \
    asm volatile("s_waitcnt vmcnt(" #VM ")" ::: "memory");                    \
    __builtin_amdgcn_s_barrier();                                             \
    if (DO_STAGE){                                                            \
      const int koff = ((K) + 2) * 32;                                        \
      ld_g2l_16(ga0 + koff, alw + (SB)*4096);                                 \
      ld_g2l_16(ga1 + koff, alw + (SB)*4096 + 512);                           \
      ld_g2l_16(gb0 + koff, blw + (SB)*4096);                                 \
      ld_g2l_16(gb1 + koff, blw + (SB)*4096 + 512);                           \
    }                                                                         \
    const unsigned short* alc = &al[(CUR)*4096];                              \
    const unsigned short* blc = &bl[(CUR)*4096];                              \
    bf16x8 af[4], bf[4];                                                      \
    _Pragma("unroll")                                                         \
    for (int i = 0; i < 4; i++){                                              \
      af[i] = *(const bf16x8*)&alc[(wm*64 + i*16 + l15)*32 + (quad ^ swz)*8]; \
      bf[i] = *(const bf16x8*)&blc[(wn*64 + i*16 + l15)*32 + (quad ^ swz)*8]; \
    }                                                                         \
    if (z == 2){                                                              \
      _Pragma("unroll")                                                       \
      for (int mi = 0; mi < 4; mi++)                                          \
        _Pragma("unroll")                                                     \
        for (int ni = 0; ni < 4; ni++)                                        \
          acc[mi][ni] = __builtin_amdgcn_mfma_f32_16x16x32_bf16(af[mi], bf[ni], acc[mi][ni], 0, 0, 0); \
    } else {                                                                  \
      _Pragma("unroll")                                                       \
      for (int mi = 0; mi < 4; mi++)                                          \
        _Pragma("unroll")                                                     \
        for (int ni = 0; ni < 4; ni++)                                        \
          acc[mi][ni] = __builtin_amdgcn_mfma_f32_16x16x32_bf16(bf[ni], af[mi], acc[mi][ni], 0, 0, 0); \
    }                                                                         \
  }

  for (int k = 0; k < 30; k += 3){
    K_ITER(k,     0, 2, 1, 4)
    K_ITER(k + 1, 1, 0, 1, 4)
    K_ITER(k + 2, 2, 1, 1, 4)
  }
  K_ITER(30, 0, 0, 0, 4)   // no stage; wait stage(30)
  K_ITER(31, 1, 0, 0, 0)   // no stage; drain stage(31)
#undef K_ITER

  const int index = idxp[0];
  if (z == 2){
    // V^T: [bh][d][s], lane holds 4 consecutive s_ -> ushort4
    #pragma unroll
    for (int ni = 0; ni < 4; ni++){
      const int n = n0 + wn*64 + ni*16 + l15;
      const float biasv = bias[n] + emb[index*HH + n];
      const int h = n >> 6, d = n & 63;
      #pragma unroll
      for (int mi = 0; mi < 4; mi++){
        const int g  = m0 + wm*64 + mi*16 + quad*4;   // 4 consecutive s (4-aligned)
        const int b_ = g >> 11;
        const int s_ = g & (SS - 1);
        const int bh = b_*NHH + h;
        const f32x4 a = acc[mi][ni];
        ushort4 o;
        o.x = f2bf(a[0] + biasv); o.y = f2bf(a[1] + biasv);
        o.z = f2bf(a[2] + biasv); o.w = f2bf(a[3] + biasv);
        *(ushort4*)&wsq[VT_OFF + (size_t)(bh*HDD + d)*SS + s_] = o;
      }
    }
  } else {
    // Q/K: [bh][s][d], swapped acc: lane holds 4 consecutive d at fixed s -> ushort4
    const float oscale = (z==0) ? 0.18033688011112042f : 1.0f;  // 0.125*log2(e)
    const size_t obase = (z==0) ? (size_t)Q_OFF : (size_t)K_OFF;
    #pragma unroll
    for (int mi = 0; mi < 4; mi++){
      const int sg = m0 + wm*64 + mi*16 + l15;        // s-row (from B-operand col)
      const int b_ = sg >> 11;
      const int s_ = sg & (SS - 1);
      #pragma unroll
      for (int ni = 0; ni < 4; ni++){
        const int nb = n0 + wn*64 + ni*16 + quad*4;   // 4 consecutive n (4-aligned)
        const int h  = nb >> 6, d0 = nb & 63;         // no h-cross (d0 % 4 == 0)
        const int bh = b_*NHH + h;
        const float4 b4 = *(const float4*)&bias[nb];
        const float4 e4 = *(const float4*)&emb[index*HH + nb];
        const f32x4 a = acc[mi][ni];
        ushort4 o;
        o.x = f2bf((a[0] + b4.x + e4.x) * oscale);
        o.y = f2bf((a[1] + b4.y + e4.y) * oscale);
        o.z = f2bf((a[2] + b4.z + e4.z) * oscale);
        o.w = f2bf((a[3] + b4.w + e4.w) * oscale);
        *(ushort4*)&wsq[obase + (size_t)(bh*SS + s_)*HDD + d0] = o;
      }
    }
  }
}

// ---------------- kernel 3: flash attention, 16q/wave, 8-wave blocks ----------------
// (R2 known-good version: 112 µs measured.)
#define ST_P 40   // P^T row stride (shorts): 80B
__global__ __launch_bounds__(512, 6) void attn_mfma(
    const unsigned short* __restrict__ ws16,
    const float* __restrict__ mask, float* __restrict__ out){
  __shared__ __align__(16) unsigned short kb[2][32*64];   // [kt][d], swizzled, 2x4KB
  __shared__ __align__(16) unsigned short vb[2][64*32];   // [d][kt], linear,   2x4KB
  __shared__ __align__(16) unsigned short pb[8][16*ST_P]; // per-wave P^T [q][kt], 10.24KB
  __shared__ __align__(16) float mlds[SS];                // mask row * log2e, 8KB

  const int tid  = threadIdx.x;
  const int wave = tid >> 6;
  const int lane = tid & 63;
  const int quad = lane >> 4;
  const int l15  = lane & 15;

  // XCD-aware swizzle (bijective: 1024 % 8 == 0): each head's 16 blocks on one XCD.
  const int bid  = (blockIdx.x & 7)*128 + (blockIdx.x >> 3);
  const int qb   = bid & 15;                 // 16 q-blocks of 128 rows per bh
  const int bh   = bid >> 4;
  const int b    = bh >> 4, h = bh & 15;
  const int q0   = qb*128 + wave*16;         // this wave's first q row
  const float LOG2E = 1.4426950408889634f;

  const unsigned short* Qg = ws16 + Q_OFF  + (size_t)bh*SS*HDD;
  const unsigned short* Kg = ws16 + K_OFF  + (size_t)bh*SS*HDD;
  const unsigned short* Vg = ws16 + VT_OFF + (size_t)bh*HDD*SS;
  const float* maskB = mask + b*SS;

  // stage mask row * log2e (512 threads x float4 = 8KB)
  {
    float4 m4 = ((const float4*)maskB)[tid];
    m4.x*=LOG2E; m4.y*=LOG2E; m4.z*=LOG2E; m4.w*=LOG2E;
    *(float4*)&mlds[tid*4] = m4;
  }

  // resident Q fragments: B-operand (n=q=l15, k=d=h2*32+quad*8+j)
  bf16x8 aq[2];
  #pragma unroll
  for (int h2 = 0; h2 < 2; h2++)
    aq[h2] = *(const bf16x8*)(Qg + (size_t)(q0 + l15)*HDD + h2*32 + quad*8);

  // staging role split: waves 0-3 stage K (32 x 128B), waves 4-7 stage V (64 x 64B).
  // K source col pre-XOR-swizzled so linear dest yields LDS[kt][col ^ ((kt&7)<<4)].
  const unsigned short* sSrc;
  unsigned short* sDst;
  int sAdv;
  if (tid < 256){
    const int kr = tid >> 3, kp = tid & 7;
    sSrc = Kg + (size_t)kr*HDD + ((((kp*16) ^ ((kr&7)<<4)))>>1);
    sDst = &kb[0][0] + tid*8;                // 16B per thread, linear
    sAdv = 32*HDD;
  } else {
    const int t = tid - 256;
    const int vr = t >> 2, vp = t & 3;
    sSrc = Vg + (size_t)vr*SS + vp*8;
    sDst = &vb[0][0] + t*8;
    sAdv = 32;
  }
  unsigned short* pw = &pb[wave][0];

  f32x4 O[4] = {};               // O^T: elem (d=dg*16+quad*4+r, q=l15)
  float lacc = 0.f;

  // prologue: stage chunk 0 into buffer 0 (syncthreads drains vmcnt)
  ld_g2l_16(sSrc, sDst);
  const unsigned short* sp = sSrc + sAdv;
  __syncthreads();

  #pragma unroll 2
  for (int ch = 0; ch < 64; ++ch){
    const int cur = ch & 1;
    const int ktb = ch*32;
    if (ch < 63){                // issue next-chunk stage BEFORE compute (overlap)
      ld_g2l_16(sp, sDst + (cur^1)*2048);
      sp += sAdv;
    }
    const unsigned short* kcur = &kb[cur][0];
    const unsigned short* vcur = &vb[cur][0];

    // K fragments: A-operand (m=kt=fi*16+l15, k=d), swizzled read (conflict-free)
    bf16x8 ka[2][2];
    #pragma unroll
    for (int fi = 0; fi < 2; fi++)
      #pragma unroll
      for (int h2 = 0; h2 < 2; h2++){
        const int colb = (h2*64 + quad*16) ^ ((l15 & 7) << 4);
        ka[fi][h2] = *(const bf16x8*)&kcur[(fi*16 + l15)*64 + (colb>>1)];
      }

    // S^T = K·Q^T with C init = mask*log2e -> p = exp2(st) -> P^T to LDS
    #pragma unroll
    for (int fi = 0; fi < 2; fi++){
      f32x4 st = *(const f32x4*)&mlds[ktb + fi*16 + quad*4];  // same-addr broadcast
      st = __builtin_amdgcn_mfma_f32_16x16x32_bf16(ka[fi][0], aq[0], st, 0,0,0);
      st = __builtin_amdgcn_mfma_f32_16x16x32_bf16(ka[fi][1], aq[1], st, 0,0,0);
      f32x4 p;
      #pragma unroll
      for (int r = 0; r < 4; r++) p[r] = __builtin_amdgcn_exp2f(st[r]);
      lacc += (p[0] + p[1]) + (p[2] + p[3]);
      uint2 w; w.x = pk2bf(p[0], p[1]); w.y = pk2bf(p[2], p[3]);
      *(uint2*)&pw[l15*ST_P + fi*16 + quad*4] = w;
    }

    // V^T fragments: A-operand (m=d=dg*16+l15, k=kt=quad*8+j), 64B rows
    bf16x8 va[4];
    #pragma unroll
    for (int dg = 0; dg < 4; dg++)
      va[dg] = *(const bf16x8*)&vcur[(dg*16 + l15)*32 + quad*8];

    // O^T += V^T · P^T  (intra-wave LDS round-trip, wave-ordered, no barrier)
    {
      bf16x8 bp = *(const bf16x8*)&pw[l15*ST_P + quad*8];
      #pragma unroll
      for (int dg = 0; dg < 4; dg++)
        O[dg] = __builtin_amdgcn_mfma_f32_16x16x32_bf16(va[dg], bp, O[dg], 0,0,0);
    }

    __syncthreads();   // all waves done reading cur; next-chunk stage drained
  }

  // row sum: reduce lacc across quads (lanes with same l15 share q)
  float lq = lacc;
  lq += __shfl_xor(lq, 16);
  lq += __shfl_xor(lq, 32);
  const float inv = 1.0f / lq;

  // epilogue: scale by 1/l, write ctx [B,S,H] fp32 as float4 per dg
  float* op = out + ((size_t)b*SS + q0 + l15)*HH + h*HDD + quad*4;
  #pragma unroll
  for (int dg = 0; dg < 4; dg++){
    f32x4 v = O[dg];
    float4 o; o.x = v[0]*inv; o.y = v[1]*inv; o.z = v[2]*inv; o.w = v[3]*inv;
    *(float4*)(op + dg*16) = o;
  }
}

extern "C" void kernel_launch(void* const* d_in, const int* in_sizes, int n_in,
                              void* d_out, int out_size, void* d_ws, size_t ws_size,
                              hipStream_t stream){
  const float* hs   = (const float*)d_in[0];
  const float* mask = (const float*)d_in[1];
  const float* Wq   = (const float*)d_in[2];
  const float* bq   = (const float*)d_in[3];
  const float* Wk   = (const float*)d_in[4];
  const float* bk   = (const float*)d_in[5];
  const float* Wv   = (const float*)d_in[6];
  const float* bv   = (const float*)d_in[7];
  const float* qe   = (const float*)d_in[8];
  const float* ke   = (const float*)d_in[9];
  const float* ve   = (const float*)d_in[10];
  const int*   idx  = (const int*)d_in[11];
  unsigned short* ws16 = (unsigned short*)d_ws;
  float* out = (float*)d_out;

  convert_x<<<M_TOT*HH/4/256, 256, 0, stream>>>(hs, ws16 + XB_OFF);
  dim3 gt(HH/64, HH/64, 3);
  convert_wt<<<gt, 256, 0, stream>>>(Wq, Wk, Wv, ws16 + WT_OFF);

  dim3 g2(M_TOT/128, HH/128, 3);
  qkv_gemm<<<g2, 256, 0, stream>>>(ws16, ws16, bq, bk, bv, qe, ke, ve, idx);

  attn_mfma<<<BB*NHH*SS/128, 512, 0, stream>>>(ws16, mask, out);
}